// Round 1
// baseline (86.241 us; speedup 1.0000x reference)
//
#include <hip/hip_runtime.h>

#define WID 256
#define HEI 256
#define CH  64
#define GRP 8
#define CPG 8
#define ND  9

__global__ __launch_bounds__(256, 2)
void cost_volume_kernel(const float* __restrict__ L,
                        const float* __restrict__ R,
                        const float* __restrict__ disp,
                        float* __restrict__ out) {
    __shared__ float sR[CH * WID];   // 64 KB: right row, all 64 channels

    const int bh  = blockIdx.x;
    const int b   = bh >> 8;
    const int h   = bh & 255;
    const int tid = threadIdx.x;

    // ---- stage feat_right[b, :, h, :] into LDS, float4-coalesced ----
    {
        const float4* R4 = reinterpret_cast<const float4*>(R);
        float4* s4 = reinterpret_cast<float4*>(sR);
        const size_t bbase4 = (size_t)b * CH * (HEI * WID / 4) + (size_t)h * (WID / 4);
        #pragma unroll
        for (int i = 0; i < 16; ++i) {
            const int idx = tid + i * 256;       // 0..4095, idx = c*64 + w4
            const int c  = idx >> 6;
            const int w4 = idx & 63;
            s4[idx] = R4[bbase4 + (size_t)c * (HEI * WID / 4) + w4];
        }
    }
    __syncthreads();

    const int w = tid;
    const float dv   = disp[((size_t)b * HEI + h) * WID + w];
    const float base = (float)w - dv;
    const float fb   = floorf(base);
    const float frac = base - fb;
    const int   fib  = (int)fb;

    // per-offset left/right lerp weights with zero-padding validity
    float wl[ND], wr[ND];
    #pragma unroll
    for (int d = 0; d < ND; ++d) {
        const int x0 = fib + 4 - d;   // off_d = d - 4
        const int x1 = x0 + 1;
        wl[d] = (x0 >= 0 && x0 < WID) ? (1.0f - frac) : 0.0f;
        wr[d] = (x1 >= 0 && x1 < WID) ? frac : 0.0f;
    }
    // window [fib-4, fib+5] fully in-bounds?
    const bool interior = (fib >= 4) && (fib <= WID - 6);

    const size_t lbase = (((size_t)b * CH) * HEI + h) * WID + w;

    #pragma unroll 1
    for (int g = 0; g < GRP; ++g) {
        float acc[ND];
        #pragma unroll
        for (int d = 0; d < ND; ++d) acc[d] = 0.0f;

        // preload the 8 left channels of this group (coalesced)
        float lf[CPG];
        #pragma unroll
        for (int k = 0; k < CPG; ++k)
            lf[k] = L[lbase + (size_t)(g * CPG + k) * (HEI * WID)];

        #pragma unroll
        for (int k = 0; k < CPG; ++k) {
            const int c = g * CPG + k;
            float rv[10];
            if (interior) {
                const int rb = c * WID + fib - 4;
                #pragma unroll
                for (int j = 0; j < 10; ++j) rv[j] = sR[rb + j];
            } else {
                #pragma unroll
                for (int j = 0; j < 10; ++j) {
                    int x = fib - 4 + j;
                    x = min(max(x, 0), WID - 1);
                    rv[j] = sR[c * WID + x];
                }
            }
            const float lv = lf[k];
            #pragma unroll
            for (int d = 0; d < ND; ++d)
                acc[d] = fmaf(lv, fmaf(rv[9 - d], wr[d], rv[8 - d] * wl[d]), acc[d]);
        }

        const size_t og = ((size_t)(b * GRP + g) * ND) * (HEI * WID) + (size_t)h * WID + w;
        #pragma unroll
        for (int d = 0; d < ND; ++d)
            out[og + (size_t)d * (HEI * WID)] = acc[d] * 0.125f;
    }
}

extern "C" void kernel_launch(void* const* d_in, const int* in_sizes, int n_in,
                              void* d_out, int out_size, void* d_ws, size_t ws_size,
                              hipStream_t stream) {
    const float* feat_left  = (const float*)d_in[0];
    const float* feat_right = (const float*)d_in[1];
    const float* disp_init  = (const float*)d_in[2];
    float* out = (float*)d_out;

    const int B = 8;
    dim3 grid(B * HEI);
    dim3 block(256);
    cost_volume_kernel<<<grid, block, 0, stream>>>(feat_left, feat_right, disp_init, out);
}

// Round 2
// 70.669 us; speedup vs baseline: 1.2204x; 1.2204x over previous
//
#include <hip/hip_runtime.h>

#define WID 256
#define HEI 256
#define CH  64
#define GRP 8
#define CPG 8
#define ND  9
#define HW  (HEI * WID)

__global__ __launch_bounds__(256, 4)
void cost_volume_kernel(const float* __restrict__ L,
                        const float* __restrict__ R,
                        const float* __restrict__ disp,
                        float* __restrict__ out) {
    // double-buffered per-group staging: 2 x 8 channels x 256 w x 4B = 16 KB
    __shared__ float sR[2][CPG * WID];

    const int bh   = blockIdx.x;
    const int b    = bh >> 8;
    const int h    = bh & 255;
    const int tid  = threadIdx.x;
    const int wv   = tid >> 6;       // wave id 0..3
    const int lane = tid & 63;

    const float4* R4 = reinterpret_cast<const float4*>(R);
    const size_t bbase4 = (size_t)b * CH * (HW / 4) + (size_t)h * (WID / 4);

    // Stage group g's 8 channel-rows into sR[buf]: each wave stages 2 rows,
    // one global_load_lds(16B) per row (64 lanes x 16B = 1024B = one row).
#define STAGE(gidx, bufidx)                                                      \
    do {                                                                         \
        _Pragma("unroll")                                                        \
        for (int i_ = 0; i_ < 2; ++i_) {                                         \
            const int cc_ = (gidx) * CPG + wv * 2 + i_;                          \
            const float4* gsrc_ = R4 + bbase4 + (size_t)cc_ * (HW / 4) + lane;   \
            __builtin_amdgcn_global_load_lds(                                    \
                (const __attribute__((address_space(1))) void*)gsrc_,            \
                (__attribute__((address_space(3))) void*)&sR[bufidx][(wv * 2 + i_) * WID], \
                16, 0, 0);                                                       \
        }                                                                        \
    } while (0)

    const int w = tid;
    const float dv   = disp[(size_t)b * HW + (size_t)h * WID + w];
    const float base = (float)w - dv;
    const float fb   = floorf(base);
    const float frac = base - fb;
    const int   fib  = (int)fb;
    const bool interior = (fib >= 4) && (fib <= WID - 6);

    const size_t lbase = ((size_t)b * CH * HEI + h) * WID + w;
    const size_t obase = ((size_t)(b * GRP) * ND) * HW + (size_t)h * WID + w;

    STAGE(0, 0);
    __syncthreads();

    #pragma unroll 1
    for (int g = 0; g < GRP; ++g) {
        // issue next group's staging early; the end-of-iter barrier drains it
        if (g + 1 < GRP) STAGE(g + 1, (g + 1) & 1);

        // left channels of this group (coalesced dword loads)
        float lf[CPG];
        #pragma unroll
        for (int k = 0; k < CPG; ++k)
            lf[k] = L[lbase + (size_t)(g * CPG + k) * HW];

        const float* sb = sR[g & 1];

        // S[j] = sum_c l_c * r_c[fib-4+j],  j = 0..9  (weights factored out)
        float S[10];
        #pragma unroll
        for (int j = 0; j < 10; ++j) S[j] = 0.0f;

        if (interior) {
            #pragma unroll
            for (int k = 0; k < CPG; ++k) {
                const int rb = k * WID + fib - 4;
                const float lv = lf[k];
                #pragma unroll
                for (int j = 0; j < 10; ++j)
                    S[j] = fmaf(lv, sb[rb + j], S[j]);
            }
        } else {
            #pragma unroll
            for (int k = 0; k < CPG; ++k) {
                const float lv = lf[k];
                #pragma unroll
                for (int j = 0; j < 10; ++j) {
                    int x = fib - 4 + j;
                    x = min(max(x, 0), WID - 1);
                    S[j] = fmaf(lv, sb[k * WID + x], S[j]);
                }
            }
        }

        // combine per offset d: x0 = fib + 4 - d (tap j = 8-d), x1 = x0+1
        const size_t og = obase + (size_t)g * ND * HW;
        #pragma unroll
        for (int d = 0; d < ND; ++d) {
            const int x0 = fib + 4 - d;
            const int x1 = x0 + 1;
            const float wl = (x0 >= 0 && x0 < WID) ? (1.0f - frac) : 0.0f;
            const float wr = (x1 >= 0 && x1 < WID) ? frac : 0.0f;
            const float v = fmaf(wl, S[8 - d], wr * S[9 - d]) * 0.125f;
            __builtin_nontemporal_store(v, &out[og + (size_t)d * HW]);
        }

        __syncthreads();
    }
#undef STAGE
}

extern "C" void kernel_launch(void* const* d_in, const int* in_sizes, int n_in,
                              void* d_out, int out_size, void* d_ws, size_t ws_size,
                              hipStream_t stream) {
    const float* feat_left  = (const float*)d_in[0];
    const float* feat_right = (const float*)d_in[1];
    const float* disp_init  = (const float*)d_in[2];
    float* out = (float*)d_out;

    dim3 grid(8 * HEI);
    dim3 block(256);
    cost_volume_kernel<<<grid, block, 0, stream>>>(feat_left, feat_right, disp_init, out);
}